// Round 1
// baseline (23175.877 us; speedup 1.0000x reference)
//
#include <hip/hip_runtime.h>
#include <hip/hip_bf16.h>
#include <stdint.h>
#include <stddef.h>

// Persistent LSTM kernel for MI355X (gfx950).
// 256 WGs x 256 threads, one per CU (all co-resident -> global spin barrier ok).
// WG wg owns hidden units [wg*4, wg*4+4): 16 gate rows (i,f,g,o x 4 units).
// Weights (bf16) live in LDS pre-swizzled into MFMA B-fragment order.
// h broadcast via global bf16 double buffer in d_ws; c never leaves registers.

#define NWG   256
#define UPW   4            // hidden units per WG
#define ROWS  16           // 4 gates * UPW
#define BATCH 64
#define TT    512
#define II    512
#define HH    1024
#define NSTEP 1024         // T * NUM_LAYERS
#define HSZ   (BATCH*HH)   // elems per h buffer (bf16)

typedef __attribute__((ext_vector_type(8))) short  bf16x8;
typedef __attribute__((ext_vector_type(4))) float  f32x4;

__device__ __forceinline__ short f2bf(float f) {
    unsigned u = __float_as_uint(f);
    u += 0x7fffu + ((u >> 16) & 1u);       // RNE
    return (short)(u >> 16);
}

__device__ __forceinline__ bf16x8 cvt8(f32x4 lo, f32x4 hi) {
    bf16x8 r;
    r[0] = f2bf(lo[0]); r[1] = f2bf(lo[1]); r[2] = f2bf(lo[2]); r[3] = f2bf(lo[3]);
    r[4] = f2bf(hi[0]); r[5] = f2bf(hi[1]); r[6] = f2bf(hi[2]); r[7] = f2bf(hi[3]);
    return r;
}

__global__ __launch_bounds__(256, 1)
void lstm_persist(const float* __restrict__ x,
                  const float* __restrict__ Ww,
                  const float* __restrict__ bw,
                  const float* __restrict__ Uw,
                  const float* __restrict__ bu,
                  float* __restrict__ out,
                  unsigned int* cnt,
                  short* hbuf)
{
    // LDS: Uw slice 32KB + Ww slice 16KB + gates 5KB + bias + flag  (~53KB)
    __shared__ __align__(16) short ldsU[ROWS*HH];   // [kc(32)][lane(64)][8]
    __shared__ __align__(16) short ldsW[ROWS*II];   // [kc(16)][lane(64)][8]
    __shared__ float ldsG[BATCH*20];                // gates staging, pad 16->20
    __shared__ float ldsB[ROWS];
    __shared__ int   abortFlag;

    const int tid = threadIdx.x;
    const int wg  = blockIdx.x;
    const int wv  = tid >> 6;       // wave 0..3 -> m-tile
    const int ln  = tid & 63;

    if (tid == 0) abortFlag = 0;

    // ---- load weight slices into LDS, bf16, pre-swizzled to B-frag order ----
    // B-frag (16x16x32): lane l holds B[k = kc*32 + (l>>4)*8 + j][n = l&15],
    // stored contiguously: offset = (kc*64 + (q*16 + r))*8 + j   (conflict-free b128 reads)
    for (int idx = tid; idx < ROWS*HH; idx += 256) {
        int r = idx >> 10, k = idx & (HH - 1);
        int gr = (r >> 2) * HH + wg * UPW + (r & 3);     // gate-major global row
        int kc = k >> 5, q = (k >> 3) & 3, j = k & 7;
        ldsU[(kc*64 + q*16 + r)*8 + j] = f2bf(Uw[(size_t)gr*HH + k]);
    }
    for (int idx = tid; idx < ROWS*II; idx += 256) {
        int r = idx >> 9, k = idx & (II - 1);
        int gr = (r >> 2) * HH + wg * UPW + (r & 3);
        int kc = k >> 5, q = (k >> 3) & 3, j = k & 7;
        ldsW[(kc*64 + q*16 + r)*8 + j] = f2bf(Ww[(size_t)gr*II + k]);
    }
    if (tid < ROWS) {
        int gr = (tid >> 2) * HH + wg * UPW + (tid & 3);
        ldsB[tid] = bw[gr] + bu[gr];
    }
    __syncthreads();

    const int mrow = wv * 16 + (ln & 15);   // batch row this lane loads for A-frags
    const int kq   = (ln >> 4) * 8;         // k sub-offset within a 32-chunk
    const int eu   = tid & 3;               // elementwise: unit
    const int eb   = tid >> 2;              // elementwise: batch
    const int gu   = wg * UPW + eu;         // global hidden index
    float c0 = 0.f;                         // cell state for (eb, gu), forever local
    f32x4 gx = {0.f, 0.f, 0.f, 0.f};        // x-part of gates, reused for 2 layer steps

    float* out0 = out;
    float* out1 = out + (size_t)NSTEP * BATCH * HH;

    for (int s = 0; s < NSTEP; ++s) {
        const int t = s >> 1;

        if ((s & 1) == 0) {
            // gates_x = x_t @ Ww.T  — independent of h: overlap with barrier wait
            f32x4 aE = {0,0,0,0}, aO = {0,0,0,0};
            const float* xp = x + ((size_t)mrow * TT + t) * II + kq;
            #pragma unroll
            for (int kc = 0; kc < 16; kc += 2) {
                f32x4 u0 = *(const f32x4*)(xp + kc*32);
                f32x4 u1 = *(const f32x4*)(xp + kc*32 + 4);
                f32x4 v0 = *(const f32x4*)(xp + kc*32 + 32);
                f32x4 v1 = *(const f32x4*)(xp + kc*32 + 36);
                bf16x8 a0 = cvt8(u0, u1);
                bf16x8 a1 = cvt8(v0, v1);
                bf16x8 b0 = *(const bf16x8*)&ldsW[(kc*64 + ln)*8];
                bf16x8 b1 = *(const bf16x8*)&ldsW[((kc+1)*64 + ln)*8];
                aE = __builtin_amdgcn_mfma_f32_16x16x32_bf16(a0, b0, aE, 0, 0, 0);
                aO = __builtin_amdgcn_mfma_f32_16x16x32_bf16(a1, b1, aO, 0, 0, 0);
            }
            gx = aE + aO;
        }

        // ---- grid barrier: wait for all WGs to have finished step s-1 ----
        if (tid == 0 && s > 0) {
            unsigned target = (unsigned)NWG * (unsigned)s;
            long guard = 0; unsigned v;
            do {
                v = __hip_atomic_load(cnt, __ATOMIC_ACQUIRE, __HIP_MEMORY_SCOPE_AGENT);
            } while (v < target && ++guard < 5000000L);
            if (v < target) abortFlag = 1;   // never hang the harness
        }
        __syncthreads();
        if (abortFlag) break;

        // ---- gates = gx + h_prev @ Uw.T  (K=1024, 32 chunks, 2 indep MFMA chains) ----
        const short* hp = hbuf + (size_t)(s & 1) * HSZ + (size_t)mrow * HH + kq;
        f32x4 aE = gx, aO = {0,0,0,0};
        #pragma unroll
        for (int kc = 0; kc < 32; kc += 2) {
            bf16x8 a0 = *(const bf16x8*)(hp + kc*32);
            bf16x8 a1 = *(const bf16x8*)(hp + (kc+1)*32);
            bf16x8 b0 = *(const bf16x8*)&ldsU[(kc*64 + ln)*8];
            bf16x8 b1 = *(const bf16x8*)&ldsU[((kc+1)*64 + ln)*8];
            aE = __builtin_amdgcn_mfma_f32_16x16x32_bf16(a0, b0, aE, 0, 0, 0);
            aO = __builtin_amdgcn_mfma_f32_16x16x32_bf16(a1, b1, aO, 0, 0, 0);
        }
        f32x4 acc = aE + aO;

        // ---- stage gates to LDS (C/D layout: col n = ln&15, row m = wv*16 + q*4 + r) ----
        {
            int n = ln & 15, qq = ln >> 4;
            #pragma unroll
            for (int r = 0; r < 4; ++r)
                ldsG[(wv*16 + qq*4 + r) * 20 + n] = acc[r];
        }
        __syncthreads();

        // ---- elementwise cell update, write outputs + h broadcast ----
        {
            float gi = ldsG[eb*20 + eu]        + ldsB[eu];
            float gf = ldsG[eb*20 + 4  + eu]   + ldsB[4 + eu];
            float gg = ldsG[eb*20 + 8  + eu]   + ldsB[8 + eu];
            float go = ldsG[eb*20 + 12 + eu]   + ldsB[12 + eu];
            float si = 1.f / (1.f + __expf(-gi));
            float sf = 1.f / (1.f + __expf(-gf));
            float so = 1.f / (1.f + __expf(-go));
            c0 = c0 * sf + si * tanhf(gg);
            float h = so * tanhf(c0);
            size_t ob = ((size_t)s * BATCH + eb) * HH + gu;
            out0[ob] = h;
            out1[ob] = c0;
            hbuf[(size_t)((s & 1) ^ 1) * HSZ + (size_t)eb * HH + gu] = f2bf(h);
        }
        __syncthreads();   // drains all stores (vmcnt(0)) before the arrive

        if (tid == 0)
            __hip_atomic_fetch_add(cnt, 1u, __ATOMIC_RELEASE, __HIP_MEMORY_SCOPE_AGENT);
    }
}

extern "C" void kernel_launch(void* const* d_in, const int* in_sizes, int n_in,
                              void* d_out, int out_size, void* d_ws, size_t ws_size,
                              hipStream_t stream)
{
    const float* x  = (const float*)d_in[0];
    const float* Ww = (const float*)d_in[1];
    const float* bw = (const float*)d_in[2];
    const float* Uw = (const float*)d_in[3];
    const float* bu = (const float*)d_in[4];
    float* out = (float*)d_out;

    // ws layout: [0,128) barrier counter; [128, 128 + 2*HSZ*2) h double buffer (bf16)
    unsigned int* cnt  = (unsigned int*)d_ws;
    short*        hbuf = (short*)((char*)d_ws + 128);

    hipMemsetAsync(d_ws, 0, 128 + (size_t)2 * HSZ * sizeof(short), stream);
    lstm_persist<<<NWG, 256, 0, stream>>>(x, Ww, bw, Uw, bu, out, cnt, hbuf);
}